// Round 3
// baseline (341.706 us; speedup 1.0000x reference)
//
#include <hip/hip_runtime.h>

#define D_IN 128
#define D_HID 256
#define CH 1024          // scan chunk size (elements per scan block)

// ---------------------------------------------------------------------------
// CSR construction: degree histogram -> decoupled 3-phase prefix scan ->
// cursor scatter
// ---------------------------------------------------------------------------

__global__ void k_hist(const int* __restrict__ dst, int* __restrict__ deg, int E) {
  int e = blockIdx.x * blockDim.x + threadIdx.x;
  if (e < E) atomicAdd(&deg[dst[e]], 1);
}

// phase 1: per-chunk sums. 256 thr, 4 elems/thread.
__global__ __launch_bounds__(256) void k_csum(const int* __restrict__ deg,
                                              int* __restrict__ csum, int n) {
  __shared__ int ws[4];
  int t = threadIdx.x, lane = t & 63, w = t >> 6;
  int base = blockIdx.x * CH + t * 4;
  int s = 0;
  #pragma unroll
  for (int j = 0; j < 4; ++j) { int i = base + j; s += (i < n) ? deg[i] : 0; }
  #pragma unroll
  for (int off = 32; off > 0; off >>= 1) s += __shfl_down(s, off, 64);
  if (lane == 0) ws[w] = s;
  __syncthreads();
  if (t == 0) csum[blockIdx.x] = ws[0] + ws[1] + ws[2] + ws[3];
}

// phase 2: exclusive scan of up to 64 chunk sums in one wave.
__global__ void k_coff(const int* __restrict__ csum, int* __restrict__ coff, int nb) {
  int lane = threadIdx.x & 63;
  int v = (lane < nb) ? csum[lane] : 0;
  int x = v;
  #pragma unroll
  for (int off = 1; off < 64; off <<= 1) {
    int u = __shfl_up(x, off, 64);
    if (lane >= off) x += u;
  }
  if (lane < nb) coff[lane] = x - v;   // exclusive
}

// phase 3: per-chunk scan + chunk offset -> rs[i+1]; rs[0]=0.
__global__ __launch_bounds__(256) void k_scanw(const int* __restrict__ deg,
                                               const int* __restrict__ coff,
                                               int* __restrict__ rs, int n) {
  __shared__ int ws[4];
  int t = threadIdx.x, lane = t & 63, w = t >> 6;
  int base = blockIdx.x * CH + t * 4;
  int d[4];
  #pragma unroll
  for (int j = 0; j < 4; ++j) { int i = base + j; d[j] = (i < n) ? deg[i] : 0; }
  int tt = d[0] + d[1] + d[2] + d[3];
  int x = tt;
  #pragma unroll
  for (int off = 1; off < 64; off <<= 1) {
    int u = __shfl_up(x, off, 64);
    if (lane >= off) x += u;
  }
  if (lane == 63) ws[w] = x;
  __syncthreads();
  if (t == 0) { int s = 0;
    #pragma unroll
    for (int j = 0; j < 4; ++j) { int tmp = ws[j]; ws[j] = s; s += tmp; } }
  __syncthreads();
  int excl = ws[w] + (x - tt) + coff[blockIdx.x];
  #pragma unroll
  for (int j = 0; j < 4; ++j) {
    int i = base + j;
    excl += d[j];
    if (i < n) rs[i + 1] = excl;   // inclusive up to i -> rs[i+1]
  }
  if (blockIdx.x == 0 && t == 0) rs[0] = 0;
}

__global__ void k_scatter(const int* __restrict__ src, const int* __restrict__ dst,
                          const int* __restrict__ rs, int* __restrict__ cursor,
                          int* __restrict__ esrc, int E) {
  int e = blockIdx.x * blockDim.x + threadIdx.x;
  if (e < E) {
    int d = dst[e];
    int pos = rs[d] + atomicAdd(&cursor[d], 1);
    esrc[pos] = src[e];
  }
}

// ---------------------------------------------------------------------------
// Layer-1 aggregation: mean of x over in-edges. One wave per node.
// lane owns 2 floats of D_IN=128 -> each edge read = 512B contiguous.
// Unrolled x4: 4 row-gathers in flight per wave (latency hiding).
// ---------------------------------------------------------------------------
__global__ void k_agg1(const float* __restrict__ X, const int* __restrict__ rs,
                       const int* __restrict__ esrc, float* __restrict__ M1, int n) {
  int wid = (blockIdx.x * blockDim.x + threadIdx.x) >> 6;
  int lane = threadIdx.x & 63;
  if (wid >= n) return;
  int s0 = rs[wid], s1 = rs[wid + 1];
  float ax0 = 0.f, ay0 = 0.f, ax1 = 0.f, ay1 = 0.f;
  int e = s0;
  for (; e + 3 < s1; e += 4) {
    int i0 = esrc[e + 0], i1 = esrc[e + 1], i2 = esrc[e + 2], i3 = esrc[e + 3];
    float2 v0 = *(const float2*)(X + (size_t)i0 * D_IN + lane * 2);
    float2 v1 = *(const float2*)(X + (size_t)i1 * D_IN + lane * 2);
    float2 v2 = *(const float2*)(X + (size_t)i2 * D_IN + lane * 2);
    float2 v3 = *(const float2*)(X + (size_t)i3 * D_IN + lane * 2);
    ax0 += v0.x; ay0 += v0.y;
    ax1 += v1.x; ay1 += v1.y;
    ax0 += v2.x; ay0 += v2.y;
    ax1 += v3.x; ay1 += v3.y;
  }
  for (; e < s1; ++e) {
    int s = esrc[e];
    float2 v = *(const float2*)(X + (size_t)s * D_IN + lane * 2);
    ax0 += v.x; ay0 += v.y;
  }
  int d = s1 - s0;
  float inv = 1.0f / (float)(d > 1 ? d : 1);
  float2 o; o.x = (ax0 + ax1) * inv; o.y = (ay0 + ay1) * inv;
  *(float2*)(M1 + (size_t)wid * D_IN + lane * 2) = o;
}

// ---------------------------------------------------------------------------
// Layer-1 GEMM (fused pair): H = relu(X @ Ws + M1 @ Wn + b1)
// block = 256 thr, tile 64 nodes x 256 cols, K-chunks of 16 in LDS,
// 8x8 micro-tile per thread. ~40.7KB LDS -> 3 blocks/CU (one full round
// at grid=782).
// ---------------------------------------------------------------------------
#define BM 64
#define KC 16

__global__ __launch_bounds__(256) void k_gemm1(
    const float* __restrict__ X, const float* __restrict__ M1,
    const float* __restrict__ Ws, const float* __restrict__ Wn,
    const float* __restrict__ b1, float* __restrict__ H, int n) {
  __shared__ float Xs[KC][BM + 4];   // +4 pad: keeps 16B align, 2-way banks (free)
  __shared__ float Ms[KC][BM + 4];
  __shared__ float Bs[KC][D_HID];
  __shared__ float Bn[KC][D_HID];
  int tid = threadIdx.x;
  int tm = tid >> 5;        // 0..7  : node group
  int tn = tid & 31;        // 0..31 : col group
  int base = blockIdx.x * BM;

  float acc[8][8];
  #pragma unroll
  for (int r = 0; r < 8; ++r)
    #pragma unroll
    for (int c = 0; c < 8; ++c) acc[r][c] = 0.f;

  for (int kt = 0; kt < D_IN; kt += KC) {
    // A tiles (transpose to k-major): 64 nodes x 16 k, one float4/thread each
    {
      int node = tid >> 2;          // 0..63
      int sub  = tid & 3;           // k-group of 4
      int gn = base + node; if (gn > n - 1) gn = n - 1;
      float4 vx = *(const float4*)(X  + (size_t)gn * D_IN + kt + sub * 4);
      float4 vm = *(const float4*)(M1 + (size_t)gn * D_IN + kt + sub * 4);
      Xs[sub * 4 + 0][node] = vx.x; Xs[sub * 4 + 1][node] = vx.y;
      Xs[sub * 4 + 2][node] = vx.z; Xs[sub * 4 + 3][node] = vx.w;
      Ms[sub * 4 + 0][node] = vm.x; Ms[sub * 4 + 1][node] = vm.y;
      Ms[sub * 4 + 2][node] = vm.z; Ms[sub * 4 + 3][node] = vm.w;
    }
    // B tiles (k-major already): 16 k x 256 cols, 4 float4/thread each
    #pragma unroll
    for (int i = 0; i < 4; ++i) {
      int flat = tid + i * 256;     // 0..1023
      int row = flat >> 6;          // 0..15
      int col4 = (flat & 63) * 4;
      *(float4*)&Bs[row][col4] = *(const float4*)(Ws + (size_t)(kt + row) * D_HID + col4);
      *(float4*)&Bn[row][col4] = *(const float4*)(Wn + (size_t)(kt + row) * D_HID + col4);
    }
    __syncthreads();

    #pragma unroll 4
    for (int kk = 0; kk < KC; ++kk) {
      float ax[8], am[8], bs[8], bn[8];
      *(float4*)&ax[0] = *(const float4*)&Xs[kk][tm * 8];
      *(float4*)&ax[4] = *(const float4*)&Xs[kk][tm * 8 + 4];
      *(float4*)&am[0] = *(const float4*)&Ms[kk][tm * 8];
      *(float4*)&am[4] = *(const float4*)&Ms[kk][tm * 8 + 4];
      *(float4*)&bs[0] = *(const float4*)&Bs[kk][tn * 4];
      *(float4*)&bs[4] = *(const float4*)&Bs[kk][128 + tn * 4];
      *(float4*)&bn[0] = *(const float4*)&Bn[kk][tn * 4];
      *(float4*)&bn[4] = *(const float4*)&Bn[kk][128 + tn * 4];
      #pragma unroll
      for (int r = 0; r < 8; ++r)
        #pragma unroll
        for (int c = 0; c < 8; ++c)
          acc[r][c] += ax[r] * bs[c] + am[r] * bn[c];
    }
    __syncthreads();
  }

  float4 bb0 = *(const float4*)(b1 + tn * 4);
  float4 bb1 = *(const float4*)(b1 + 128 + tn * 4);
  #pragma unroll
  for (int r = 0; r < 8; ++r) {
    int node = base + tm * 8 + r;
    if (node < n) {
      float4 o0, o1;
      o0.x = fmaxf(acc[r][0] + bb0.x, 0.f);
      o0.y = fmaxf(acc[r][1] + bb0.y, 0.f);
      o0.z = fmaxf(acc[r][2] + bb0.z, 0.f);
      o0.w = fmaxf(acc[r][3] + bb0.w, 0.f);
      o1.x = fmaxf(acc[r][4] + bb1.x, 0.f);
      o1.y = fmaxf(acc[r][5] + bb1.y, 0.f);
      o1.z = fmaxf(acc[r][6] + bb1.z, 0.f);
      o1.w = fmaxf(acc[r][7] + bb1.w, 0.f);
      *(float4*)(H + (size_t)node * D_HID + tn * 4) = o0;
      *(float4*)(H + (size_t)node * D_HID + 128 + tn * 4) = o1;
    }
  }
}

// ---------------------------------------------------------------------------
// Layer-2 projection: S[n] = H[n] @ W2s + b2   (2 floats)
//                     P[n] = H[n] @ W2n        (2 floats)
// mean_neigh(H) @ W2n == mean_neigh(H @ W2n)  (linearity) -> aggregate P,
// cutting the per-edge gather from 1KB to 8B (655MB -> 5MB edge traffic).
// One wave per node; lane owns 4 floats of D_HID.
// ---------------------------------------------------------------------------
__global__ void k_proj(const float* __restrict__ H,
                       const float* __restrict__ W2s, const float* __restrict__ W2n,
                       const float* __restrict__ b2,
                       float* __restrict__ S, float* __restrict__ P, int n) {
  int wid = (blockIdx.x * blockDim.x + threadIdx.x) >> 6;
  int lane = threadIdx.x & 63;
  if (wid >= n) return;
  float4 h = *(const float4*)(H + (size_t)wid * D_HID + lane * 4);
  int k0 = lane * 4;
  float2 ws0 = *(const float2*)(W2s + (size_t)(k0 + 0) * 2);
  float2 ws1 = *(const float2*)(W2s + (size_t)(k0 + 1) * 2);
  float2 ws2 = *(const float2*)(W2s + (size_t)(k0 + 2) * 2);
  float2 ws3 = *(const float2*)(W2s + (size_t)(k0 + 3) * 2);
  float2 wn0 = *(const float2*)(W2n + (size_t)(k0 + 0) * 2);
  float2 wn1 = *(const float2*)(W2n + (size_t)(k0 + 1) * 2);
  float2 wn2 = *(const float2*)(W2n + (size_t)(k0 + 2) * 2);
  float2 wn3 = *(const float2*)(W2n + (size_t)(k0 + 3) * 2);
  float s0 = h.x * ws0.x + h.y * ws1.x + h.z * ws2.x + h.w * ws3.x;
  float s1 = h.x * ws0.y + h.y * ws1.y + h.z * ws2.y + h.w * ws3.y;
  float p0 = h.x * wn0.x + h.y * wn1.x + h.z * wn2.x + h.w * wn3.x;
  float p1 = h.x * wn0.y + h.y * wn1.y + h.z * wn2.y + h.w * wn3.y;
  #pragma unroll
  for (int off = 32; off > 0; off >>= 1) {
    s0 += __shfl_down(s0, off, 64);
    s1 += __shfl_down(s1, off, 64);
    p0 += __shfl_down(p0, off, 64);
    p1 += __shfl_down(p1, off, 64);
  }
  if (lane == 0) {
    *(float2*)(S + (size_t)wid * 2) = make_float2(s0 + b2[0], s1 + b2[1]);
    *(float2*)(P + (size_t)wid * 2) = make_float2(p0, p1);
  }
}

// ---------------------------------------------------------------------------
// Layer-2 aggregation over projected P (8B/edge), fused with final add.
// One thread per node; unrolled x4 for MLP. P is 400KB -> L2-resident.
// ---------------------------------------------------------------------------
__global__ void k_agg2(const float* __restrict__ S, const float* __restrict__ P,
                       const int* __restrict__ rs, const int* __restrict__ esrc,
                       float* __restrict__ out, int n) {
  int nid = blockIdx.x * blockDim.x + threadIdx.x;
  if (nid >= n) return;
  int s0 = rs[nid], s1 = rs[nid + 1];
  float a00 = 0.f, a01 = 0.f, a10 = 0.f, a11 = 0.f;
  int e = s0;
  for (; e + 3 < s1; e += 4) {
    int i0 = esrc[e + 0], i1 = esrc[e + 1], i2 = esrc[e + 2], i3 = esrc[e + 3];
    float2 p0 = *(const float2*)(P + (size_t)i0 * 2);
    float2 p1 = *(const float2*)(P + (size_t)i1 * 2);
    float2 p2 = *(const float2*)(P + (size_t)i2 * 2);
    float2 p3 = *(const float2*)(P + (size_t)i3 * 2);
    a00 += p0.x; a01 += p0.y;
    a10 += p1.x; a11 += p1.y;
    a00 += p2.x; a01 += p2.y;
    a10 += p3.x; a11 += p3.y;
  }
  for (; e < s1; ++e) {
    int s = esrc[e];
    float2 p = *(const float2*)(P + (size_t)s * 2);
    a00 += p.x; a01 += p.y;
  }
  int d = s1 - s0;
  float inv = 1.0f / (float)(d > 1 ? d : 1);
  float2 sv = *(const float2*)(S + (size_t)nid * 2);
  float2 o; o.x = sv.x + (a00 + a10) * inv; o.y = sv.y + (a01 + a11) * inv;
  *(float2*)(out + (size_t)nid * 2) = o;
}

// ---------------------------------------------------------------------------
extern "C" void kernel_launch(void* const* d_in, const int* in_sizes, int n_in,
                              void* d_out, int out_size, void* d_ws, size_t ws_size,
                              hipStream_t stream) {
  const float* X   = (const float*)d_in[0];
  const int*   src = (const int*)d_in[1];
  const int*   dst = (const int*)d_in[2];
  const float* W1s = (const float*)d_in[3];
  const float* W1n = (const float*)d_in[4];
  const float* b1  = (const float*)d_in[5];
  const float* W2s = (const float*)d_in[6];
  const float* W2n = (const float*)d_in[7];
  const float* b2  = (const float*)d_in[8];
  float* out = (float*)d_out;

  const int N = in_sizes[0] / D_IN;   // 50000
  const int E = in_sizes[1];          // 640000
  const int NB = (N + CH - 1) / CH;   // scan chunks (49, must be <= 64)

  // workspace layout (all 16B-aligned), ~81 MB total
  int* deg    = (int*)d_ws;               // [N]
  int* cursor = deg + N;                  // [N]
  int* rs     = cursor + N;               // [N+1] (padded to N+8)
  int* csum   = rs + (N + 8);             // [64]
  int* coff   = csum + 64;                // [64]
  int* esrc   = coff + 64;                // [E]
  float* S    = (float*)(esrc + E);       // [N,2]
  float* P    = S + (size_t)N * 2;        // [N,2]
  float* M1   = P + (size_t)N * 2;        // [N, D_IN]
  float* H    = M1 + (size_t)N * D_IN;    // [N, D_HID]

  hipMemsetAsync(deg, 0, sizeof(int) * (size_t)2 * N, stream);  // deg + cursor

  int eb = (E + 255) / 256;
  k_hist   <<<eb, 256, 0, stream>>>(dst, deg, E);
  k_csum   <<<NB, 256, 0, stream>>>(deg, csum, N);
  k_coff   <<<1, 64, 0, stream>>>(csum, coff, NB);
  k_scanw  <<<NB, 256, 0, stream>>>(deg, coff, rs, N);
  k_scatter<<<eb, 256, 0, stream>>>(src, dst, rs, cursor, esrc, E);
  k_agg1   <<<(N + 3) / 4, 256, 0, stream>>>(X, rs, esrc, M1, N);
  k_gemm1  <<<(N + BM - 1) / BM, 256, 0, stream>>>(X, M1, W1s, W1n, b1, H, N);
  k_proj   <<<(N + 3) / 4, 256, 0, stream>>>(H, W2s, W2n, b2, S, P, N);
  k_agg2   <<<(N + 255) / 256, 256, 0, stream>>>(S, P, rs, esrc, out, N);
}

// Round 4
// 303.414 us; speedup vs baseline: 1.1262x; 1.1262x over previous
//
#include <hip/hip_runtime.h>

#define D_IN 128
#define D_HID 256
#define CH 1024
#define MPAD 50048   // 391 * 128

typedef short bf16x8 __attribute__((ext_vector_type(8)));
typedef float f32x4 __attribute__((ext_vector_type(4)));

__device__ __forceinline__ unsigned short f2bf_rne(float x) {
  unsigned int u = __float_as_uint(x);
  unsigned int r = (u + 0x7FFFu + ((u >> 16) & 1u)) >> 16;
  return (unsigned short)r;
}
__device__ __forceinline__ float bf2f(unsigned short b) {
  return __uint_as_float(((unsigned int)b) << 16);
}

// ---------------------------------------------------------------------------
// CSR construction
// ---------------------------------------------------------------------------
__global__ void k_hist(const int* __restrict__ dst, int* __restrict__ deg, int E) {
  int e = blockIdx.x * blockDim.x + threadIdx.x;
  if (e < E) atomicAdd(&deg[dst[e]], 1);
}

__global__ __launch_bounds__(256) void k_csum(const int* __restrict__ deg,
                                              int* __restrict__ csum, int n) {
  __shared__ int ws[4];
  int t = threadIdx.x, lane = t & 63, w = t >> 6;
  int base = blockIdx.x * CH + t * 4;
  int s = 0;
  #pragma unroll
  for (int j = 0; j < 4; ++j) { int i = base + j; s += (i < n) ? deg[i] : 0; }
  #pragma unroll
  for (int off = 32; off > 0; off >>= 1) s += __shfl_down(s, off, 64);
  if (lane == 0) ws[w] = s;
  __syncthreads();
  if (t == 0) csum[blockIdx.x] = ws[0] + ws[1] + ws[2] + ws[3];
}

__global__ void k_coff(const int* __restrict__ csum, int* __restrict__ coff, int nb) {
  int lane = threadIdx.x & 63;
  int v = (lane < nb) ? csum[lane] : 0;
  int x = v;
  #pragma unroll
  for (int off = 1; off < 64; off <<= 1) {
    int u = __shfl_up(x, off, 64);
    if (lane >= off) x += u;
  }
  if (lane < nb) coff[lane] = x - v;
}

__global__ __launch_bounds__(256) void k_scanw(const int* __restrict__ deg,
                                               const int* __restrict__ coff,
                                               int* __restrict__ rs, int n) {
  __shared__ int ws[4];
  int t = threadIdx.x, lane = t & 63, w = t >> 6;
  int base = blockIdx.x * CH + t * 4;
  int d[4];
  #pragma unroll
  for (int j = 0; j < 4; ++j) { int i = base + j; d[j] = (i < n) ? deg[i] : 0; }
  int tt = d[0] + d[1] + d[2] + d[3];
  int x = tt;
  #pragma unroll
  for (int off = 1; off < 64; off <<= 1) {
    int u = __shfl_up(x, off, 64);
    if (lane >= off) x += u;
  }
  if (lane == 63) ws[w] = x;
  __syncthreads();
  if (t == 0) { int s = 0;
    #pragma unroll
    for (int j = 0; j < 4; ++j) { int tmp = ws[j]; ws[j] = s; s += tmp; } }
  __syncthreads();
  int excl = ws[w] + (x - tt) + coff[blockIdx.x];
  #pragma unroll
  for (int j = 0; j < 4; ++j) {
    int i = base + j;
    excl += d[j];
    if (i < n) rs[i + 1] = excl;
  }
  if (blockIdx.x == 0 && t == 0) rs[0] = 0;
}

__global__ void k_scatter(const int* __restrict__ src, const int* __restrict__ dst,
                          const int* __restrict__ rs, int* __restrict__ cursor,
                          int* __restrict__ esrc, int E) {
  int e = blockIdx.x * blockDim.x + threadIdx.x;
  if (e < E) {
    int d = dst[e];
    int pos = rs[d] + atomicAdd(&cursor[d], 1);
    esrc[pos] = src[e];
  }
}

// ---------------------------------------------------------------------------
// Weight conversion: Bt_hi/Bt_lo[col][k] bf16 (transposed, split) from
// [W1s(128); W1n(128)] stacked along k.
// ---------------------------------------------------------------------------
__global__ __launch_bounds__(256) void k_convW(const float* __restrict__ W1s,
                                               const float* __restrict__ W1n,
                                               unsigned short* __restrict__ Bth,
                                               unsigned short* __restrict__ Btl) {
  int k = blockIdx.x;          // 0..255
  int col = threadIdx.x;       // 0..255
  float w = (k < 128) ? W1s[(size_t)k * D_HID + col]
                      : W1n[(size_t)(k - 128) * D_HID + col];
  unsigned short hi = f2bf_rne(w);
  unsigned short lo = f2bf_rne(w - bf2f(hi));
  Bth[(size_t)col * 256 + k] = hi;
  Btl[(size_t)col * 256 + k] = lo;
}

// ---------------------------------------------------------------------------
// X conversion into A_hi/A_lo[MPAD][256] cols 0..127; zero-fill pad rows.
// One wave per row.
// ---------------------------------------------------------------------------
__global__ __launch_bounds__(256) void k_convX(const float* __restrict__ X,
                                               unsigned short* __restrict__ Ah,
                                               unsigned short* __restrict__ Al,
                                               int n) {
  int row = blockIdx.x * 4 + (threadIdx.x >> 6);
  int lane = threadIdx.x & 63;
  unsigned short* ah = Ah + (size_t)row * 256 + lane * 2;
  unsigned short* al = Al + (size_t)row * 256 + lane * 2;
  if (row < n) {
    float2 v = *(const float2*)(X + (size_t)row * D_IN + lane * 2);
    unsigned short hx = f2bf_rne(v.x), hy = f2bf_rne(v.y);
    unsigned short lx = f2bf_rne(v.x - bf2f(hx)), ly = f2bf_rne(v.y - bf2f(hy));
    *(ushort2*)ah = make_ushort2(hx, hy);
    *(ushort2*)al = make_ushort2(lx, ly);
  } else {               // pad rows: zero all 256 cols (both halves)
    ushort2 z = make_ushort2(0, 0);
    *(ushort2*)ah = z; *(ushort2*)(ah + 128) = z;
    *(ushort2*)al = z; *(ushort2*)(al + 128) = z;
  }
}

// ---------------------------------------------------------------------------
// Layer-1 aggregation: mean of X over in-edges, written as split-bf16 into
// A_hi/A_lo cols 128..255. One wave per node, lane owns 2 features.
// ---------------------------------------------------------------------------
__global__ void k_agg1(const float* __restrict__ X, const int* __restrict__ rs,
                       const int* __restrict__ esrc,
                       unsigned short* __restrict__ Ah,
                       unsigned short* __restrict__ Al, int n) {
  int wid = (blockIdx.x * blockDim.x + threadIdx.x) >> 6;
  int lane = threadIdx.x & 63;
  if (wid >= n) return;
  int s0 = rs[wid], s1 = rs[wid + 1];
  float ax0 = 0.f, ay0 = 0.f, ax1 = 0.f, ay1 = 0.f;
  int e = s0;
  for (; e + 3 < s1; e += 4) {
    int i0 = esrc[e + 0], i1 = esrc[e + 1], i2 = esrc[e + 2], i3 = esrc[e + 3];
    float2 v0 = *(const float2*)(X + (size_t)i0 * D_IN + lane * 2);
    float2 v1 = *(const float2*)(X + (size_t)i1 * D_IN + lane * 2);
    float2 v2 = *(const float2*)(X + (size_t)i2 * D_IN + lane * 2);
    float2 v3 = *(const float2*)(X + (size_t)i3 * D_IN + lane * 2);
    ax0 += v0.x; ay0 += v0.y;
    ax1 += v1.x; ay1 += v1.y;
    ax0 += v2.x; ay0 += v2.y;
    ax1 += v3.x; ay1 += v3.y;
  }
  for (; e < s1; ++e) {
    int s = esrc[e];
    float2 v = *(const float2*)(X + (size_t)s * D_IN + lane * 2);
    ax0 += v.x; ay0 += v.y;
  }
  int d = s1 - s0;
  float inv = 1.0f / (float)(d > 1 ? d : 1);
  float mx = (ax0 + ax1) * inv, my = (ay0 + ay1) * inv;
  unsigned short hx = f2bf_rne(mx), hy = f2bf_rne(my);
  unsigned short lx = f2bf_rne(mx - bf2f(hx)), ly = f2bf_rne(my - bf2f(hy));
  *(ushort2*)(Ah + (size_t)wid * 256 + 128 + lane * 2) = make_ushort2(hx, hy);
  *(ushort2*)(Al + (size_t)wid * 256 + 128 + lane * 2) = make_ushort2(lx, ly);
}

// ---------------------------------------------------------------------------
// MFMA GEMM (split-bf16, 3 terms) + fused layer-2 projection epilogue.
// Tile: 128 rows x 128 cols per block (4 waves, each 64x64), K-step 32.
// acc += Ahi*Bhi + Ahi*Blo + Alo*Bhi  (error ~2^-16 rel, fp32 accumulate)
// Epilogue: h = relu(acc + b1[col]); SP[row] += {h.W2s, h.W2n} via atomics.
// ---------------------------------------------------------------------------
#define AS1 __attribute__((address_space(1)))
#define AS3 __attribute__((address_space(3)))

__global__ __launch_bounds__(256, 3) void k_gemm1(
    const unsigned short* __restrict__ Ah, const unsigned short* __restrict__ Al,
    const unsigned short* __restrict__ Bth, const unsigned short* __restrict__ Btl,
    const float* __restrict__ b1, const float* __restrict__ W2s,
    const float* __restrict__ W2n, float* __restrict__ SP) {
  __shared__ unsigned short sAh[128][32];
  __shared__ unsigned short sAl[128][32];
  __shared__ unsigned short sBh[128][32];
  __shared__ unsigned short sBl[128][32];

  const int tid = threadIdx.x;
  const int w = tid >> 6;         // wave 0..3
  const int l = tid & 63;
  const int wm = w & 1, wn = w >> 1;
  const int m0 = blockIdx.x * 128;
  const int n0 = blockIdx.y * 128;

  f32x4 acc[4][4];
  #pragma unroll
  for (int i = 0; i < 4; ++i)
    #pragma unroll
    for (int j = 0; j < 4; ++j) acc[i][j] = (f32x4)0.f;

  const int rsub = l >> 2;            // 0..15 row within 16-row stage chunk
  const int ksub = (l & 3) * 8;       // bf16 k-offset of this lane's 16B chunk
  const int g = l >> 4;               // 0..3
  const int c = l & 15;               // 0..15
  const int kb = g * 8;               // frag k-base

  for (int kt = 0; kt < 256; kt += 32) {
    // stage 4 tiles of 128x32 bf16 via global_load_lds (16B/lane, 1KB/issue)
    #pragma unroll
    for (int j = 0; j < 2; ++j) {
      int r = w * 32 + j * 16;
      const unsigned short* ga = Ah + (size_t)(m0 + r + rsub) * 256 + kt + ksub;
      const unsigned short* gb = Al + (size_t)(m0 + r + rsub) * 256 + kt + ksub;
      const unsigned short* gc = Bth + (size_t)(n0 + r + rsub) * 256 + kt + ksub;
      const unsigned short* gd = Btl + (size_t)(n0 + r + rsub) * 256 + kt + ksub;
      __builtin_amdgcn_global_load_lds((AS1 const void*)ga, (AS3 void*)&sAh[r][0], 16, 0, 0);
      __builtin_amdgcn_global_load_lds((AS1 const void*)gb, (AS3 void*)&sAl[r][0], 16, 0, 0);
      __builtin_amdgcn_global_load_lds((AS1 const void*)gc, (AS3 void*)&sBh[r][0], 16, 0, 0);
      __builtin_amdgcn_global_load_lds((AS1 const void*)gd, (AS3 void*)&sBl[r][0], 16, 0, 0);
    }
    __syncthreads();   // drains vmcnt -> staged data visible

    bf16x8 ahi[4], alo[4];
    #pragma unroll
    for (int mi = 0; mi < 4; ++mi) {
      int arow = wm * 64 + mi * 16 + c;
      ahi[mi] = *(const bf16x8*)(&sAh[arow][kb]);
      alo[mi] = *(const bf16x8*)(&sAl[arow][kb]);
    }
    #pragma unroll
    for (int ni = 0; ni < 4; ++ni) {
      int bcol = wn * 64 + ni * 16 + c;
      bf16x8 bhi = *(const bf16x8*)(&sBh[bcol][kb]);
      bf16x8 blo = *(const bf16x8*)(&sBl[bcol][kb]);
      #pragma unroll
      for (int mi = 0; mi < 4; ++mi) {
        acc[mi][ni] = __builtin_amdgcn_mfma_f32_16x16x32_bf16(ahi[mi], bhi, acc[mi][ni], 0, 0, 0);
        acc[mi][ni] = __builtin_amdgcn_mfma_f32_16x16x32_bf16(ahi[mi], blo, acc[mi][ni], 0, 0, 0);
        acc[mi][ni] = __builtin_amdgcn_mfma_f32_16x16x32_bf16(alo[mi], bhi, acc[mi][ni], 0, 0, 0);
      }
    }
    __syncthreads();   // all frag reads done before next stage overwrites
  }

  // fused epilogue: relu(acc + b1) projected onto W2s/W2n, reduced per row
  float b1v[4]; float2 w2sv[4], w2nv[4];
  #pragma unroll
  for (int ni = 0; ni < 4; ++ni) {
    int col = n0 + wn * 64 + ni * 16 + c;
    b1v[ni] = b1[col];
    w2sv[ni] = *(const float2*)(W2s + (size_t)col * 2);
    w2nv[ni] = *(const float2*)(W2n + (size_t)col * 2);
  }
  #pragma unroll
  for (int mi = 0; mi < 4; ++mi) {
    #pragma unroll
    for (int j = 0; j < 4; ++j) {
      float s0 = 0.f, s1 = 0.f, p0 = 0.f, p1 = 0.f;
      #pragma unroll
      for (int ni = 0; ni < 4; ++ni) {
        float h = fmaxf(acc[mi][ni][j] + b1v[ni], 0.f);
        s0 += h * w2sv[ni].x; s1 += h * w2sv[ni].y;
        p0 += h * w2nv[ni].x; p1 += h * w2nv[ni].y;
      }
      #pragma unroll
      for (int off = 1; off < 16; off <<= 1) {
        s0 += __shfl_xor(s0, off, 64);
        s1 += __shfl_xor(s1, off, 64);
        p0 += __shfl_xor(p0, off, 64);
        p1 += __shfl_xor(p1, off, 64);
      }
      if (c == 0) {
        int row = m0 + wm * 64 + mi * 16 + g * 4 + j;
        float* sp = SP + (size_t)row * 4;
        atomicAdd(sp + 0, s0);
        atomicAdd(sp + 1, s1);
        atomicAdd(sp + 2, p0);
        atomicAdd(sp + 3, p1);
      }
    }
  }
}

// ---------------------------------------------------------------------------
// Layer-2 aggregation over projected P (= SP[:,2:4], 8B/edge) + final add.
// ---------------------------------------------------------------------------
__global__ void k_agg2(const float* __restrict__ SP,
                       const int* __restrict__ rs, const int* __restrict__ esrc,
                       const float* __restrict__ b2,
                       float* __restrict__ out, int n) {
  int nid = blockIdx.x * blockDim.x + threadIdx.x;
  if (nid >= n) return;
  int s0 = rs[nid], s1 = rs[nid + 1];
  float a00 = 0.f, a01 = 0.f, a10 = 0.f, a11 = 0.f;
  int e = s0;
  for (; e + 3 < s1; e += 4) {
    int i0 = esrc[e + 0], i1 = esrc[e + 1], i2 = esrc[e + 2], i3 = esrc[e + 3];
    float2 p0 = *(const float2*)(SP + (size_t)i0 * 4 + 2);
    float2 p1 = *(const float2*)(SP + (size_t)i1 * 4 + 2);
    float2 p2 = *(const float2*)(SP + (size_t)i2 * 4 + 2);
    float2 p3 = *(const float2*)(SP + (size_t)i3 * 4 + 2);
    a00 += p0.x; a01 += p0.y;
    a10 += p1.x; a11 += p1.y;
    a00 += p2.x; a01 += p2.y;
    a10 += p3.x; a11 += p3.y;
  }
  for (; e < s1; ++e) {
    int s = esrc[e];
    float2 p = *(const float2*)(SP + (size_t)s * 4 + 2);
    a00 += p.x; a01 += p.y;
  }
  int d = s1 - s0;
  float inv = 1.0f / (float)(d > 1 ? d : 1);
  float2 sv = *(const float2*)(SP + (size_t)nid * 4);
  float2 o;
  o.x = sv.x + b2[0] + (a00 + a10) * inv;
  o.y = sv.y + b2[1] + (a01 + a11) * inv;
  *(float2*)(out + (size_t)nid * 2) = o;
}

// ---------------------------------------------------------------------------
extern "C" void kernel_launch(void* const* d_in, const int* in_sizes, int n_in,
                              void* d_out, int out_size, void* d_ws, size_t ws_size,
                              hipStream_t stream) {
  const float* X   = (const float*)d_in[0];
  const int*   src = (const int*)d_in[1];
  const int*   dst = (const int*)d_in[2];
  const float* W1s = (const float*)d_in[3];
  const float* W1n = (const float*)d_in[4];
  const float* b1  = (const float*)d_in[5];
  const float* W2s = (const float*)d_in[6];
  const float* W2n = (const float*)d_in[7];
  const float* b2  = (const float*)d_in[8];
  float* out = (float*)d_out;

  const int N = in_sizes[0] / D_IN;   // 50000
  const int E = in_sizes[1];          // 640000
  const int NB = (N + CH - 1) / CH;   // 49 scan chunks (<= 64)

  // workspace layout (16B-aligned sections), ~55.4 MB total
  int* deg    = (int*)d_ws;                         // [N]
  int* cursor = deg + N;                            // [N]
  int* rs     = cursor + N;                         // [N+8]
  int* csum   = rs + (N + 8);                       // [64]
  int* coff   = csum + 64;                          // [64]
  int* esrc   = coff + 64;                          // [E]
  float* SP   = (float*)(esrc + E);                 // [MPAD][4] {S0,S1,P0,P1}
  unsigned short* Ah  = (unsigned short*)(SP + (size_t)MPAD * 4);  // [MPAD][256]
  unsigned short* Al  = Ah + (size_t)MPAD * 256;                   // [MPAD][256]
  unsigned short* Bth = Al + (size_t)MPAD * 256;                   // [256][256]
  unsigned short* Btl = Bth + 256 * 256;                           // [256][256]

  hipMemsetAsync(deg, 0, sizeof(int) * (size_t)2 * N, stream);     // deg+cursor
  hipMemsetAsync(SP, 0, sizeof(float) * (size_t)MPAD * 4, stream); // S,P accum

  int eb = (E + 255) / 256;
  k_convW  <<<256, 256, 0, stream>>>(W1s, W1n, Bth, Btl);
  k_convX  <<<MPAD / 4, 256, 0, stream>>>(X, Ah, Al, N);
  k_hist   <<<eb, 256, 0, stream>>>(dst, deg, E);
  k_csum   <<<NB, 256, 0, stream>>>(deg, csum, N);
  k_coff   <<<1, 64, 0, stream>>>(csum, coff, NB);
  k_scanw  <<<NB, 256, 0, stream>>>(deg, coff, rs, N);
  k_scatter<<<eb, 256, 0, stream>>>(src, dst, rs, cursor, esrc, E);
  k_agg1   <<<(N + 3) / 4, 256, 0, stream>>>(X, rs, esrc, Ah, Al, N);
  k_gemm1  <<<dim3(MPAD / 128, 2), 256, 0, stream>>>(Ah, Al, Bth, Btl,
                                                     b1, W2s, W2n, SP);
  k_agg2   <<<(N + 255) / 256, 256, 0, stream>>>(SP, rs, esrc, b2, out, N);
}

// Round 6
// 255.393 us; speedup vs baseline: 1.3380x; 1.1880x over previous
//
#include <hip/hip_runtime.h>

#define D_IN 128
#define D_HID 256
#define CH 1024
#define MPAD 50048   // 782 * 64

typedef short bf16x8 __attribute__((ext_vector_type(8)));
typedef float f32x4 __attribute__((ext_vector_type(4)));
typedef unsigned short ushort8 __attribute__((ext_vector_type(8)));

#define AS1 __attribute__((address_space(1)))
#define AS3 __attribute__((address_space(3)))

__device__ __forceinline__ unsigned short f2bf_rne(float x) {
  unsigned int u = __float_as_uint(x);
  unsigned int r = (u + 0x7FFFu + ((u >> 16) & 1u)) >> 16;
  return (unsigned short)r;
}
__device__ __forceinline__ float bf2f(unsigned short b) {
  return __uint_as_float(((unsigned int)b) << 16);
}

// ---------------------------------------------------------------------------
// CSR construction
// ---------------------------------------------------------------------------
__global__ void k_hist(const int* __restrict__ dst, int* __restrict__ deg, int E) {
  int e = blockIdx.x * blockDim.x + threadIdx.x;
  if (e < E) atomicAdd(&deg[dst[e]], 1);
}

__global__ __launch_bounds__(256) void k_csum(const int* __restrict__ deg,
                                              int* __restrict__ csum, int n) {
  __shared__ int ws[4];
  int t = threadIdx.x, lane = t & 63, w = t >> 6;
  int base = blockIdx.x * CH + t * 4;
  int s = 0;
  #pragma unroll
  for (int j = 0; j < 4; ++j) { int i = base + j; s += (i < n) ? deg[i] : 0; }
  #pragma unroll
  for (int off = 32; off > 0; off >>= 1) s += __shfl_down(s, off, 64);
  if (lane == 0) ws[w] = s;
  __syncthreads();
  if (t == 0) csum[blockIdx.x] = ws[0] + ws[1] + ws[2] + ws[3];
}

__global__ void k_coff(const int* __restrict__ csum, int* __restrict__ coff, int nb) {
  int lane = threadIdx.x & 63;
  int v = (lane < nb) ? csum[lane] : 0;
  int x = v;
  #pragma unroll
  for (int off = 1; off < 64; off <<= 1) {
    int u = __shfl_up(x, off, 64);
    if (lane >= off) x += u;
  }
  if (lane < nb) coff[lane] = x - v;
}

__global__ __launch_bounds__(256) void k_scanw(const int* __restrict__ deg,
                                               const int* __restrict__ coff,
                                               int* __restrict__ rs, int n) {
  __shared__ int ws[4];
  int t = threadIdx.x, lane = t & 63, w = t >> 6;
  int base = blockIdx.x * CH + t * 4;
  int d[4];
  #pragma unroll
  for (int j = 0; j < 4; ++j) { int i = base + j; d[j] = (i < n) ? deg[i] : 0; }
  int tt = d[0] + d[1] + d[2] + d[3];
  int x = tt;
  #pragma unroll
  for (int off = 1; off < 64; off <<= 1) {
    int u = __shfl_up(x, off, 64);
    if (lane >= off) x += u;
  }
  if (lane == 63) ws[w] = x;
  __syncthreads();
  if (t == 0) { int s = 0;
    #pragma unroll
    for (int j = 0; j < 4; ++j) { int tmp = ws[j]; ws[j] = s; s += tmp; } }
  __syncthreads();
  int excl = ws[w] + (x - tt) + coff[blockIdx.x];
  #pragma unroll
  for (int j = 0; j < 4; ++j) {
    int i = base + j;
    excl += d[j];
    if (i < n) rs[i + 1] = excl;
  }
  if (blockIdx.x == 0 && t == 0) rs[0] = 0;
}

__global__ void k_scatter(const int* __restrict__ src, const int* __restrict__ dst,
                          const int* __restrict__ rs, int* __restrict__ cursor,
                          int* __restrict__ esrc, int E) {
  int e = blockIdx.x * blockDim.x + threadIdx.x;
  if (e < E) {
    int d = dst[e];
    int pos = rs[d] + atomicAdd(&cursor[d], 1);
    esrc[pos] = src[e];
  }
}

// ---------------------------------------------------------------------------
// Weight conversion: Bt_hi/Bt_lo[col][k] bf16 (transposed, split) from
// [W1s(128); W1n(128)] stacked along k.
// ---------------------------------------------------------------------------
__global__ __launch_bounds__(256) void k_convW(const float* __restrict__ W1s,
                                               const float* __restrict__ W1n,
                                               unsigned short* __restrict__ Bth,
                                               unsigned short* __restrict__ Btl) {
  int k = blockIdx.x;          // 0..255
  int col = threadIdx.x;       // 0..255
  float w = (k < 128) ? W1s[(size_t)k * D_HID + col]
                      : W1n[(size_t)(k - 128) * D_HID + col];
  unsigned short hi = f2bf_rne(w);
  unsigned short lo = f2bf_rne(w - bf2f(hi));
  Bth[(size_t)col * 256 + k] = hi;
  Btl[(size_t)col * 256 + k] = lo;
}

// ---------------------------------------------------------------------------
// Layer-1 aggregation: mean of X over in-edges -> split-bf16 Mh/Ml[MPAD][128].
// One wave per node, lane owns 2 features, unrolled x4 for latency hiding.
// ---------------------------------------------------------------------------
__global__ void k_agg1(const float* __restrict__ X, const int* __restrict__ rs,
                       const int* __restrict__ esrc,
                       unsigned short* __restrict__ Mh,
                       unsigned short* __restrict__ Ml, int n) {
  int wid = (blockIdx.x * blockDim.x + threadIdx.x) >> 6;
  int lane = threadIdx.x & 63;
  if (wid >= n) return;
  int s0 = rs[wid], s1 = rs[wid + 1];
  float ax0 = 0.f, ay0 = 0.f, ax1 = 0.f, ay1 = 0.f;
  int e = s0;
  for (; e + 3 < s1; e += 4) {
    int i0 = esrc[e + 0], i1 = esrc[e + 1], i2 = esrc[e + 2], i3 = esrc[e + 3];
    float2 v0 = *(const float2*)(X + (size_t)i0 * D_IN + lane * 2);
    float2 v1 = *(const float2*)(X + (size_t)i1 * D_IN + lane * 2);
    float2 v2 = *(const float2*)(X + (size_t)i2 * D_IN + lane * 2);
    float2 v3 = *(const float2*)(X + (size_t)i3 * D_IN + lane * 2);
    ax0 += v0.x; ay0 += v0.y;
    ax1 += v1.x; ay1 += v1.y;
    ax0 += v2.x; ay0 += v2.y;
    ax1 += v3.x; ay1 += v3.y;
  }
  for (; e < s1; ++e) {
    int s = esrc[e];
    float2 v = *(const float2*)(X + (size_t)s * D_IN + lane * 2);
    ax0 += v.x; ay0 += v.y;
  }
  int d = s1 - s0;
  float inv = 1.0f / (float)(d > 1 ? d : 1);
  float mx = (ax0 + ax1) * inv, my = (ay0 + ay1) * inv;
  unsigned short hx = f2bf_rne(mx), hy = f2bf_rne(my);
  unsigned short lx = f2bf_rne(mx - bf2f(hx)), ly = f2bf_rne(my - bf2f(hy));
  *(ushort2*)(Mh + (size_t)wid * 128 + lane * 2) = make_ushort2(hx, hy);
  *(ushort2*)(Ml + (size_t)wid * 128 + lane * 2) = make_ushort2(lx, ly);
}

// ---------------------------------------------------------------------------
// MFMA GEMM (split-bf16, 3 terms), BM=64 x BN=256 (full width), K=256.
// k<128: A comes from fp32 X, converted to split-bf16 in-kernel.
// k>=128: A comes from Mh/Ml via global_load_lds (pre-permuted source so the
//         LDS layout is lane-linear: frag for lane l sits at byte l*16).
// Fused epilogue: h=relu(acc+b1); SP[row] = {h.W2s, h.W2n} (no atomics).
// ---------------------------------------------------------------------------
__global__ __launch_bounds__(256, 3) void k_gemm1(
    const float* __restrict__ X,
    const unsigned short* __restrict__ Mh, const unsigned short* __restrict__ Ml,
    const unsigned short* __restrict__ Bth, const unsigned short* __restrict__ Btl,
    const float* __restrict__ b1, const float* __restrict__ W2s,
    const float* __restrict__ W2n, float* __restrict__ SP, int n) {
  // subtile = 16 rows x 32 k, stored lane-linear: (g=kchunk, c=row) at short
  // offset g*128 + c*8 == lane*8  ->  frag read is linear 16B/lane (2-way, free)
  __shared__ __align__(16) unsigned short sAh[4][512];
  __shared__ __align__(16) unsigned short sAl[4][512];
  __shared__ __align__(16) unsigned short sBh[16][512];
  __shared__ __align__(16) unsigned short sBl[16][512];

  const int tid = threadIdx.x;
  const int w = tid >> 6;        // wave 0..3: owns rows w*16..w*16+15
  const int l = tid & 63;
  const int c = l & 15;          // row-in-subtile (stage) / col-in-tile (epi)
  const int g = l >> 4;          // k-chunk (stage) / row-quad (epi)
  const int m0 = blockIdx.x * 64;

  f32x4 acc[16];
  #pragma unroll
  for (int i = 0; i < 16; ++i) acc[i] = (f32x4)0.f;

  const int arow = m0 + w * 16 + c;               // this lane's staged A row
  const int xrow = (arow < n) ? arow : (n - 1);   // clamp pad rows for X reads

  for (int ks = 0; ks < 8; ++ks) {
    const int kt = ks * 32;
    // ---- stage A subtile w ----
    if (kt < 128) {
      const float* src = X + (size_t)xrow * D_IN + kt + g * 8;
      float4 u0 = *(const float4*)(src);
      float4 u1 = *(const float4*)(src + 4);
      float v[8] = {u0.x, u0.y, u0.z, u0.w, u1.x, u1.y, u1.z, u1.w};
      ushort8 hh, ll;
      #pragma unroll
      for (int i = 0; i < 8; ++i) {
        unsigned short h = f2bf_rne(v[i]);
        hh[i] = h;
        ll[i] = f2bf_rne(v[i] - bf2f(h));
      }
      *(ushort8*)(&sAh[w][l * 8]) = hh;
      *(ushort8*)(&sAl[w][l * 8]) = ll;
    } else {
      const unsigned short* mh = Mh + (size_t)arow * 128 + (kt - 128) + g * 8;
      const unsigned short* ml = Ml + (size_t)arow * 128 + (kt - 128) + g * 8;
      __builtin_amdgcn_global_load_lds((AS1 const void*)mh, (AS3 void*)&sAh[w][0], 16, 0, 0);
      __builtin_amdgcn_global_load_lds((AS1 const void*)ml, (AS3 void*)&sAl[w][0], 16, 0, 0);
    }
    // ---- stage B subtiles w*4 .. w*4+3 ----
    #pragma unroll
    for (int q = 0; q < 4; ++q) {
      int ni = w * 4 + q;
      const unsigned short* bh = Bth + (size_t)(ni * 16 + c) * 256 + kt + g * 8;
      const unsigned short* bl = Btl + (size_t)(ni * 16 + c) * 256 + kt + g * 8;
      __builtin_amdgcn_global_load_lds((AS1 const void*)bh, (AS3 void*)&sBh[ni][0], 16, 0, 0);
      __builtin_amdgcn_global_load_lds((AS1 const void*)bl, (AS3 void*)&sBl[ni][0], 16, 0, 0);
    }
    __syncthreads();

    bf16x8 ah = *(const bf16x8*)(&sAh[w][l * 8]);
    bf16x8 al = *(const bf16x8*)(&sAl[w][l * 8]);
    #pragma unroll
    for (int ni = 0; ni < 16; ++ni) {
      bf16x8 bh = *(const bf16x8*)(&sBh[ni][l * 8]);
      bf16x8 bl = *(const bf16x8*)(&sBl[ni][l * 8]);
      acc[ni] = __builtin_amdgcn_mfma_f32_16x16x32_bf16(ah, bh, acc[ni], 0, 0, 0);
      acc[ni] = __builtin_amdgcn_mfma_f32_16x16x32_bf16(ah, bl, acc[ni], 0, 0, 0);
      acc[ni] = __builtin_amdgcn_mfma_f32_16x16x32_bf16(al, bh, acc[ni], 0, 0, 0);
    }
    __syncthreads();
  }

  // ---- fused epilogue: relu + bias, project onto W2s/W2n, store SP ----
  float s0[4] = {0.f, 0.f, 0.f, 0.f}, s1[4] = {0.f, 0.f, 0.f, 0.f};
  float p0[4] = {0.f, 0.f, 0.f, 0.f}, p1[4] = {0.f, 0.f, 0.f, 0.f};
  #pragma unroll
  for (int ni = 0; ni < 16; ++ni) {
    int col = ni * 16 + c;
    float bb = b1[col];
    float2 ws = *(const float2*)(W2s + (size_t)col * 2);
    float2 wn = *(const float2*)(W2n + (size_t)col * 2);
    #pragma unroll
    for (int j = 0; j < 4; ++j) {
      float h = fmaxf(acc[ni][j] + bb, 0.f);
      s0[j] += h * ws.x; s1[j] += h * ws.y;
      p0[j] += h * wn.x; p1[j] += h * wn.y;
    }
  }
  #pragma unroll
  for (int j = 0; j < 4; ++j) {
    #pragma unroll
    for (int off = 1; off < 16; off <<= 1) {
      s0[j] += __shfl_xor(s0[j], off, 64);
      s1[j] += __shfl_xor(s1[j], off, 64);
      p0[j] += __shfl_xor(p0[j], off, 64);
      p1[j] += __shfl_xor(p1[j], off, 64);
    }
  }
  if (c == 0) {
    #pragma unroll
    for (int j = 0; j < 4; ++j) {
      int row = m0 + w * 16 + g * 4 + j;
      float4 o; o.x = s0[j]; o.y = s1[j]; o.z = p0[j]; o.w = p1[j];
      *(float4*)(SP + (size_t)row * 4) = o;
    }
  }
}

// ---------------------------------------------------------------------------
// Layer-2 aggregation over projected P (= SP[:,2:4], 8B/edge) + final add.
// ---------------------------------------------------------------------------
__global__ void k_agg2(const float* __restrict__ SP,
                       const int* __restrict__ rs, const int* __restrict__ esrc,
                       const float* __restrict__ b2,
                       float* __restrict__ out, int n) {
  int nid = blockIdx.x * blockDim.x + threadIdx.x;
  if (nid >= n) return;
  int s0 = rs[nid], s1 = rs[nid + 1];
  float a00 = 0.f, a01 = 0.f, a10 = 0.f, a11 = 0.f;
  int e = s0;
  for (; e + 3 < s1; e += 4) {
    int i0 = esrc[e + 0], i1 = esrc[e + 1], i2 = esrc[e + 2], i3 = esrc[e + 3];
    float2 p0 = *(const float2*)(SP + (size_t)i0 * 4 + 2);
    float2 p1 = *(const float2*)(SP + (size_t)i1 * 4 + 2);
    float2 p2 = *(const float2*)(SP + (size_t)i2 * 4 + 2);
    float2 p3 = *(const float2*)(SP + (size_t)i3 * 4 + 2);
    a00 += p0.x; a01 += p0.y;
    a10 += p1.x; a11 += p1.y;
    a00 += p2.x; a01 += p2.y;
    a10 += p3.x; a11 += p3.y;
  }
  for (; e < s1; ++e) {
    int s = esrc[e];
    float2 p = *(const float2*)(SP + (size_t)s * 4 + 2);
    a00 += p.x; a01 += p.y;
  }
  int d = s1 - s0;
  float inv = 1.0f / (float)(d > 1 ? d : 1);
  float2 sv = *(const float2*)(SP + (size_t)nid * 4);
  float2 o;
  o.x = sv.x + b2[0] + (a00 + a10) * inv;
  o.y = sv.y + b2[1] + (a01 + a11) * inv;
  *(float2*)(out + (size_t)nid * 2) = o;
}

// ---------------------------------------------------------------------------
extern "C" void kernel_launch(void* const* d_in, const int* in_sizes, int n_in,
                              void* d_out, int out_size, void* d_ws, size_t ws_size,
                              hipStream_t stream) {
  const float* X   = (const float*)d_in[0];
  const int*   src = (const int*)d_in[1];
  const int*   dst = (const int*)d_in[2];
  const float* W1s = (const float*)d_in[3];
  const float* W1n = (const float*)d_in[4];
  const float* b1  = (const float*)d_in[5];
  const float* W2s = (const float*)d_in[6];
  const float* W2n = (const float*)d_in[7];
  const float* b2  = (const float*)d_in[8];
  float* out = (float*)d_out;

  const int N = in_sizes[0] / D_IN;   // 50000
  const int E = in_sizes[1];          // 640000
  const int NB = (N + CH - 1) / CH;   // 49 scan chunks (<= 64)

  // workspace layout (16B-aligned sections), ~32 MB total
  int* deg    = (int*)d_ws;                         // [N]
  int* cursor = deg + N;                            // [N]
  int* rs     = cursor + N;                         // [N+8]
  int* csum   = rs + (N + 8);                       // [64]
  int* coff   = csum + 64;                          // [64]
  int* esrc   = coff + 64;                          // [E]
  float* SP   = (float*)(esrc + E);                 // [MPAD][4] {S0,S1,P0,P1}
  unsigned short* Mh  = (unsigned short*)(SP + (size_t)MPAD * 4);  // [MPAD][128]
  unsigned short* Ml  = Mh + (size_t)MPAD * 128;                   // [MPAD][128]
  unsigned short* Bth = Ml + (size_t)MPAD * 128;                   // [256][256]
  unsigned short* Btl = Bth + 256 * 256;                           // [256][256]

  hipMemsetAsync(deg, 0, sizeof(int) * (size_t)2 * N, stream);     // deg+cursor

  int eb = (E + 255) / 256;
  k_convW  <<<256, 256, 0, stream>>>(W1s, W1n, Bth, Btl);
  k_hist   <<<eb, 256, 0, stream>>>(dst, deg, E);
  k_csum   <<<NB, 256, 0, stream>>>(deg, csum, N);
  k_coff   <<<1, 64, 0, stream>>>(csum, coff, NB);
  k_scanw  <<<NB, 256, 0, stream>>>(deg, coff, rs, N);
  k_scatter<<<eb, 256, 0, stream>>>(src, dst, rs, cursor, esrc, E);
  k_agg1   <<<(N + 3) / 4, 256, 0, stream>>>(X, rs, esrc, Mh, Ml, N);
  k_gemm1  <<<MPAD / 64, 256, 0, stream>>>(X, Mh, Ml, Bth, Btl,
                                           b1, W2s, W2n, SP, N);
  k_agg2   <<<(N + 255) / 256, 256, 0, stream>>>(SP, rs, esrc, b2, out, N);
}